// Round 7
// baseline (43.596 us; speedup 1.0000x reference)
//
#include <hip/hip_runtime.h>

// Sobel gradient magnitude on [B=32, 1, H=1024, W=1024] f32, zero ("SAME") padding.
// Separable: Gx = vsmooth[1,2,1] ⊗ hdiff[-1,0,1]; Gy = vdiff[-1,0,1] ⊗ hsmooth[1,2,1].
// R=8 vertical register blocking (10 segment loads in flight, halo 1.25x) with
// SINGLE-WAVE blocks (64 threads x 256 cols): 16384 independent waves lets the
// scheduler pack ~32 waves/CU (vs 16 with 256-thread blocks) for latency hiding.
// XCD-aware bijective swizzle: each XCD owns 2048 consecutive blocks = 4 images.

typedef float f32x4 __attribute__((ext_vector_type(4)));

constexpr int W = 1024;
constexpr int H = 1024;
constexpr int B = 32;
constexpr int R = 8;                    // output rows per thread
constexpr int STRIPS = H / R;           // 128 strips per image
constexpr int CT = 4;                   // column tiles per row (64 lanes x 4 cols = 256)
constexpr int NBLK = B * STRIPS * CT;   // 16384 blocks (divisible by 8 XCDs)

__global__ __launch_bounds__(64) void sobel_kernel(const float* __restrict__ x,
                                                   float* __restrict__ out) {
    // Bijective XCD swizzle: HW round-robins blockIdx%8 across XCDs; remap so
    // each XCD owns a contiguous run (all column tiles + adjacent strips share L2).
    const int bid = blockIdx.x;
    const int swz = (bid & 7) * (NBLK / 8) + (bid >> 3);
    const int ct    = swz & (CT - 1);
    const int strip = (swz >> 2) & (STRIPS - 1);
    const int b     = swz >> 9;          // swz / (STRIPS*CT)
    const int r0 = strip * R;

    const int c0 = (ct << 8) + ((int)threadIdx.x << 2);  // 64 lanes x 4 cols
    const size_t img_off = (size_t)b * H * W;
    const float* __restrict__ img = x + img_off;

    const bool has_l = (c0 > 0);
    const bool has_r = (c0 + 4 < W);

    // Load R+2 = 10 row segments (rows r0-1 .. r0+8) + left/right edge scalars.
    f32x4 v[R + 2];
    float lf[R + 2], rt[R + 2];

    if (strip > 0 && strip < STRIPS - 1) {
        // Interior strip (126/128): wave-uniform fast path, unconditional loads.
        const float* rp = img + (size_t)(r0 - 1) * W;
#pragma unroll
        for (int i = 0; i < R + 2; ++i, rp += W) {
            v[i]  = *reinterpret_cast<const f32x4*>(rp + c0);
            lf[i] = has_l ? rp[c0 - 1] : 0.f;   // L1/L2 hits (neighbor lanes/blocks)
            rt[i] = has_r ? rp[c0 + 4] : 0.f;
        }
    } else {
        // Boundary strip: predicate row validity (zero padding).
#pragma unroll
        for (int i = 0; i < R + 2; ++i) {
            const int row = r0 - 1 + i;
            const bool valid = (row >= 0) && (row < H);
            const float* rp = img + (size_t)row * W;
            v[i]  = valid ? *reinterpret_cast<const f32x4*>(rp + c0) : (f32x4)(0.f);
            lf[i] = (valid && has_l) ? rp[c0 - 1] : 0.f;
            rt[i] = (valid && has_r) ? rp[c0 + 4] : 0.f;
        }
    }

    float* __restrict__ obase = out + img_off + (size_t)r0 * W + c0;

#pragma unroll
    for (int j = 0; j < R; ++j) {
        // Window rows: segments j, j+1, j+2 (image rows r0+j-1, r0+j, r0+j+1)
        const f32x4 a = v[j], m = v[j + 1], p = v[j + 2];

        // Vertical smooth t = up + 2*mid + dn; vertical diff d = dn - up
        const float tL = lf[j] + 2.f * lf[j + 1] + lf[j + 2];
        const float t0 = a.x + 2.f * m.x + p.x;
        const float t1 = a.y + 2.f * m.y + p.y;
        const float t2 = a.z + 2.f * m.z + p.z;
        const float t3 = a.w + 2.f * m.w + p.w;
        const float tR = rt[j] + 2.f * rt[j + 1] + rt[j + 2];

        const float dL = lf[j + 2] - lf[j];
        const float d0 = p.x - a.x;
        const float d1 = p.y - a.y;
        const float d2 = p.z - a.z;
        const float d3 = p.w - a.w;
        const float dR = rt[j + 2] - rt[j];

        // Horizontal: gx[k] = t[k+1] - t[k-1]; gy[k] = d[k-1] + 2*d[k] + d[k+1]
        const float gx0 = t1 - tL;
        const float gx1 = t2 - t0;
        const float gx2 = t3 - t1;
        const float gx3 = tR - t2;

        const float gy0 = dL + 2.f * d0 + d1;
        const float gy1 = d0 + 2.f * d1 + d2;
        const float gy2 = d1 + 2.f * d2 + d3;
        const float gy3 = d2 + 2.f * d3 + dR;

        f32x4 o;
        // v_sqrt_f32 (~1 ulp) — absolute threshold 0.42, exact fixup not needed
        o.x = __builtin_amdgcn_sqrtf(gx0 * gx0 + gy0 * gy0);
        o.y = __builtin_amdgcn_sqrtf(gx1 * gx1 + gy1 * gy1);
        o.z = __builtin_amdgcn_sqrtf(gx2 * gx2 + gy2 * gy2);
        o.w = __builtin_amdgcn_sqrtf(gx3 * gx3 + gy3 * gy3);

        // Nontemporal store: output never re-read; don't evict input halo from L2
        __builtin_nontemporal_store(o, reinterpret_cast<f32x4*>(obase + (size_t)j * W));
    }
}

extern "C" void kernel_launch(void* const* d_in, const int* in_sizes, int n_in,
                              void* d_out, int out_size, void* d_ws, size_t ws_size,
                              hipStream_t stream) {
    const float* x = (const float*)d_in[0];
    float* out = (float*)d_out;
    sobel_kernel<<<NBLK, 64, 0, stream>>>(x, out);
}